// Round 3
// baseline (897.584 us; speedup 1.0000x reference)
//
#include <hip/hip_runtime.h>
#include <hip/hip_bf16.h>
#include <math.h>

// Problem constants (NodeEncoder: 3-layer GAT on chess graph)
#define N_NODES 32768
#define E_PER   16384
#define T_TYPES 8
#define E_TYPED (T_TYPES * E_PER)      // 131072
#define E_TOT   (E_TYPED + N_NODES)    // 163840 (with self loops)
#define NEG_SLOPE 0.2f
#define CSR_CAP 64
#define GRID 512                       // 2 blocks/CU x 256 CUs, co-resident by construction

typedef _Float16 f16x8 __attribute__((ext_vector_type(8)));
typedef float f32x4 __attribute__((ext_vector_type(4)));

// ---------- helpers ----------
__device__ __forceinline__ float lrelu(float a) { return a > 0.0f ? a : NEG_SLOPE * a; }

__device__ __forceinline__ void osm_comb(float& m, float& z, int off) {
  float om = __shfl_xor(m, off, 64);
  float oz = __shfl_xor(z, off, 64);
  float nm = fmaxf(m, om);
  z = z * __expf(m - nm) + oz * __expf(om - nm);
  m = nm;
}

// async global->LDS, 16B per lane; lds base wave-uniform (dest = base + lane*16)
__device__ __forceinline__ void gload16(const void* g, void* l) {
  __builtin_amdgcn_global_load_lds(
      (const __attribute__((address_space(1))) void*)g,
      (__attribute__((address_space(3))) void*)l,
      16, 0, 0);
}

// grid-wide barrier: monotone counter, device-scope. Requires all blocks resident.
__device__ __forceinline__ void gridbar(int* bar, int target) {
  __threadfence();
  __syncthreads();
  if (threadIdx.x == 0) {
    atomicAdd(bar, 1);
    int it = 0;
    while (__hip_atomic_load(bar, __ATOMIC_RELAXED, __HIP_MEMORY_SCOPE_AGENT) < target) {
      __builtin_amdgcn_s_sleep(2);
      if (++it > (1 << 24)) break;   // safety valve: bounded spin (~1s) instead of hang
    }
  }
  __syncthreads();
  __threadfence();
}

// ---------- weight-prep device blocks ----------
// prep layout (floats): [0..511] v_src[h*128+i], [512..1023] v_dst[h*128+i],
//                       [1024..1059] s_edge[t*4+h], t=0..8 (8 = self loop)
__device__ void prep_blk(int b, const float* __restrict__ W, const float* __restrict__ We,
                         const float* __restrict__ asrc, const float* __restrict__ adst,
                         const float* __restrict__ aedge, float* __restrict__ prep,
                         int din, int dout) {
  int task = b * 4 + (threadIdx.x >> 6);
  int lane = threadIdx.x & 63;
  int hd = 4 * din;
  float s = 0.0f;
  if (task < 2 * hd) {
    int k = (task < hd) ? task : task - hd;
    int h = k / din, i = k % din;
    const float* a = (task < hd) ? asrc : adst;
    for (int c = lane; c < dout; c += 64)
      s += W[(size_t)i * 4 * dout + h * dout + c] * a[h * dout + c];
#pragma unroll
    for (int off = 32; off >= 1; off >>= 1) s += __shfl_xor(s, off, 64);
    if (lane == 0) prep[((task < hd) ? 0 : 512) + h * 128 + i] = s;
  } else if (task < 2 * hd + 32) {
    int k = task - 2 * hd; int t = k >> 2, h = k & 3;
    for (int c = lane; c < dout; c += 64)
      s += We[(size_t)t * 4 * dout + h * dout + c] * aedge[h * dout + c];
#pragma unroll
    for (int off = 32; off >= 1; off >>= 1) s += __shfl_xor(s, off, 64);
    if (lane == 0) prep[1024 + t * 4 + h] = s;
  } else if (task < 2 * hd + 36) {
    int h = task - 2 * hd - 32;
    for (int t = 0; t < 8; ++t)
      for (int c = lane; c < dout; c += 64)
        s += We[(size_t)t * 4 * dout + h * dout + c] * aedge[h * dout + c];
#pragma unroll
    for (int off = 32; off >= 1; off >>= 1) s += __shfl_xor(s, off, 64);
    if (lane == 0) prep[1024 + 32 + h] = s * 0.125f;   // loop edge attr = mean one-hot
  }
}

// W -> Bt[j][k] fp16 (k = h*din+i), one 64x64 transpose tile; T = [64][65] floats in LDS
__device__ void wt_blk(int jt, int kt, const float* __restrict__ W,
                       _Float16* __restrict__ Bt, int din, int dout, float* T) {
  int jb = jt * 64, kb = kt * 64;
  int KK = 4 * din;
  int tx = threadIdx.x & 63, ty4 = threadIdx.x >> 6;
  for (int r0 = 0; r0 < 64; r0 += 4) {
    int r = r0 + ty4;
    int k = kb + r, h = k / din, i = k % din;
    T[r * 65 + tx] = W[(size_t)i * 4 * dout + h * dout + jb + tx];
  }
  __syncthreads();
  for (int r0 = 0; r0 < 64; r0 += 4) {
    int r = r0 + ty4;
    Bt[(size_t)(jb + r) * KK + kb + tx] = (_Float16)T[tx * 65 + r];
  }
  __syncthreads();   // LDS reused by next unit
}

#define NB_P1 41
#define NB_P2 73
#define NB_P3 265
#define NB_W2 4
#define NB_W3 64
#define NB_Z  32
#define NB_WEIGHTS (NB_P1 + NB_P2 + NB_P3 + NB_W2 + NB_W3 + NB_Z)  // 479
#define NB_FILL 640   // E_TOT/256
#define NB_S1 8192    // N/4

// ===================================================================
// mega kernel: all phases, grid barriers between
// ===================================================================
__global__ __launch_bounds__(256, 2) void k_mega(
    const float* __restrict__ x, const int* __restrict__ ei,
    const float* __restrict__ W1, const float* __restrict__ We1,
    const float* __restrict__ as1, const float* __restrict__ ad1, const float* __restrict__ ae1,
    const float* __restrict__ b1,
    const float* __restrict__ W2, const float* __restrict__ We2,
    const float* __restrict__ as2, const float* __restrict__ ad2, const float* __restrict__ ae2,
    const float* __restrict__ b2,
    const float* __restrict__ W3, const float* __restrict__ We3,
    const float* __restrict__ as3, const float* __restrict__ ad3, const float* __restrict__ ae3,
    const float* __restrict__ b3,
    int* __restrict__ cnt, int* __restrict__ csr,
    float* __restrict__ ssrcA, float* __restrict__ sdstA,
    float* __restrict__ ssrcB, float* __restrict__ sdstB,
    float* __restrict__ prep1, float* __restrict__ prep2, float* __restrict__ prep3,
    float* __restrict__ h1, _Float16* __restrict__ h2, _Float16* __restrict__ agg3,
    _Float16* __restrict__ w2t, _Float16* __restrict__ w3t,
    float* __restrict__ dout, int* bar) {
  __shared__ __align__(16) char LB[34304];
  const int tid = threadIdx.x;
  const int lane = tid & 63, wv = tid >> 6;
  const int quad = lane >> 4, l16 = lane & 15;
  const int srow = lane >> 3, scolB = (lane & 7) * 16;
  const int wm = (wv >> 1) * 32, wn = (wv & 1) * 64;   // 64x128 MFMA tiles (P3/P5)

  // ===== P0: weight prep + W transposes + cnt zero =====
  for (int vb = blockIdx.x; vb < NB_WEIGHTS; vb += GRID) {
    int b = vb;
    if (b < NB_P1) { prep_blk(b, W1, We1, as1, ad1, ae1, prep1, 16, 32); continue; }
    b -= NB_P1;
    if (b < NB_P2) { prep_blk(b, W2, We2, as2, ad2, ae2, prep2, 32, 128); continue; }
    b -= NB_P2;
    if (b < NB_P3) { prep_blk(b, W3, We3, as3, ad3, ae3, prep3, 128, 512); continue; }
    b -= NB_P3;
    if (b < NB_W2) { wt_blk(b & 1, b >> 1, W2, w2t, 32, 128, (float*)LB); continue; }
    b -= NB_W2;
    if (b < NB_W3) { wt_blk(b & 7, b >> 3, W3, w3t, 128, 512, (float*)LB); continue; }
    b -= NB_W3;
    int4 z; z.x = z.y = z.z = z.w = 0;
    reinterpret_cast<int4*>(cnt)[b * 256 + tid] = z;
  }
  gridbar(bar, 1 * GRID);

  // ===== P1: bucket-CSR fill + layer-1 scores (-> A buffers) =====
  {
    float* vv = (float*)(LB + 33792);   // 128 floats
    for (int j = tid; j < 128; j += 256) {
      int s = j >> 4, i = j & 15;
      vv[j] = prep1[(s & 3) * 128 + i + ((s >= 4) ? 512 : 0)];
    }
    __syncthreads();
    for (int vb = blockIdx.x; vb < NB_FILL + NB_S1; vb += GRID) {
      if (vb < NB_FILL) {
        int e = vb * 256 + tid;
        int src, dst, t;
        if (e < E_TYPED) { t = e >> 14; int j = e & (E_PER - 1); src = ei[2 * t * E_PER + j]; dst = ei[(2 * t + 1) * E_PER + j]; }
        else { src = dst = e - E_TYPED; t = 8; }
        dst &= (N_NODES - 1);
        int pos = atomicAdd(cnt + dst, 1);
        if (pos < CSR_CAP)
          csr[dst * CSR_CAP + pos] = (src & (N_NODES - 1)) | (t << 16);
      } else {
        int n = (vb - NB_FILL) * 4 + wv;
        const float* row = x + (size_t)n * 16;
        float p0 = 0, p1 = 0, p2 = 0, p3 = 0, p4 = 0, p5 = 0, p6 = 0, p7 = 0;
        for (int c = lane; c < 16; c += 64) {
          float v = row[c];
          p0 += v * vv[0 * 16 + c]; p1 += v * vv[1 * 16 + c];
          p2 += v * vv[2 * 16 + c]; p3 += v * vv[3 * 16 + c];
          p4 += v * vv[4 * 16 + c]; p5 += v * vv[5 * 16 + c];
          p6 += v * vv[6 * 16 + c]; p7 += v * vv[7 * 16 + c];
        }
#pragma unroll
        for (int off = 32; off >= 1; off >>= 1) {
          p0 += __shfl_xor(p0, off, 64); p1 += __shfl_xor(p1, off, 64);
          p2 += __shfl_xor(p2, off, 64); p3 += __shfl_xor(p3, off, 64);
          p4 += __shfl_xor(p4, off, 64); p5 += __shfl_xor(p5, off, 64);
          p6 += __shfl_xor(p6, off, 64); p7 += __shfl_xor(p7, off, 64);
        }
        if (lane == 0) {
          float* a = ssrcA + (size_t)n * 4; a[0] = p0; a[1] = p1; a[2] = p2; a[3] = p3;
          float* bq = sdstA + (size_t)n * 4; bq[0] = p4; bq[1] = p5; bq[2] = p6; bq[3] = p7;
        }
      }
    }
  }
  gridbar(bar, 2 * GRID);

  // ===== P2: agg1 (LDS only) + gemm1 + layer-2 scores (-> B buffers). 512 units. =====
  {
    float* Asf = (float*)LB;              // [64][68] f32
    float* Bsf = (float*)(LB + 17408);    // [64][36] f32
    float* se_ = (float*)(LB + 33792);    // 40 f32
    const int nb = blockIdx.x * 64;
    for (int j = tid; j < 40; j += 256) se_[j] = (j < 36) ? prep1[1024 + j] : 0.0f;
    for (int idx = tid; idx < 2048; idx += 256) {
      int k = idx >> 5, j = idx & 31, h = k >> 4, i = k & 15;
      Bsf[k * 36 + j] = W1[i * 128 + h * 32 + j];
    }
    __syncthreads();
    for (int g = 0; g < 16; ++g) {
      int nl = wv * 16 + g, n = nb + nl;
      int kd = min(cnt[n], CSR_CAP);
      int o0 = n * CSR_CAP;
      const float* sdp = sdstA + (size_t)n * 4;
      float sd0 = sdp[0], sd1 = sdp[1], sd2 = sdp[2], sd3 = sdp[3];
      float a0 = -1e30f, a1 = -1e30f, a2 = -1e30f, a3 = -1e30f;
      float m0 = -1e30f, m1 = -1e30f, m2 = -1e30f, m3 = -1e30f;
      float z0 = 0, z1 = 0, z2 = 0, z3 = 0;
      int sx = 0;
      if (lane < kd) {
        int ent = csr[o0 + lane];
        sx = ent & (N_NODES - 1);
        int tt = (ent >> 16) & 15;
        const float4 sv = *reinterpret_cast<const float4*>(ssrcA + (size_t)sx * 4);
        a0 = lrelu(sv.x + sd0 + se_[tt * 4 + 0]);
        a1 = lrelu(sv.y + sd1 + se_[tt * 4 + 1]);
        a2 = lrelu(sv.z + sd2 + se_[tt * 4 + 2]);
        a3 = lrelu(sv.w + sd3 + se_[tt * 4 + 3]);
        m0 = a0; m1 = a1; m2 = a2; m3 = a3;
        z0 = 1; z1 = 1; z2 = 1; z3 = 1;
      }
#pragma unroll
      for (int off = 32; off >= 1; off >>= 1) {
        osm_comb(m0, z0, off); osm_comb(m1, z1, off);
        osm_comb(m2, z2, off); osm_comb(m3, z3, off);
      }
      float r0 = (z0 > 0.0f) ? 1.0f / z0 : 0.0f;
      float r1 = (z1 > 0.0f) ? 1.0f / z1 : 0.0f;
      float r2 = (z2 > 0.0f) ? 1.0f / z2 : 0.0f;
      float r3 = (z3 > 0.0f) ? 1.0f / z3 : 0.0f;
      float w0 = 0, w1 = 0, w2 = 0, w3 = 0;
      if (lane < kd) {
        w0 = __expf(a0 - m0) * r0; w1 = __expf(a1 - m1) * r1;
        w2 = __expf(a2 - m2) * r2; w3 = __expf(a3 - m3) * r3;
      }
      float acc = 0.0f;
      for (int e = 0; e < kd; ++e) {
        int se2 = __shfl(sx, e, 64);
        float u0 = __shfl(w0, e, 64), u1 = __shfl(w1, e, 64);
        float u2 = __shfl(w2, e, 64), u3 = __shfl(w3, e, 64);
        float v = x[(size_t)se2 * 16 + (lane & 15)];
        int hh = lane >> 4;
        float wa = (hh == 0) ? u0 : (hh == 1) ? u1 : (hh == 2) ? u2 : u3;
        acc += wa * v;
      }
      Asf[nl * 68 + lane] = acc;
    }
    __syncthreads();
    // gemm1: 64x32, K=64 from LDS
    int m = tid >> 2, j0 = (tid & 3) * 8;
    float a8[8] = {};
    for (int kk = 0; kk < 64; ++kk) {
      float a = Asf[m * 68 + kk];
#pragma unroll
      for (int q = 0; q < 8; ++q) a8[q] = fmaf(a, Bsf[kk * 36 + j0 + q], a8[q]);
    }
    __syncthreads();
    float* ot = Asf;                      // reuse as [64][33]
#pragma unroll
    for (int q = 0; q < 8; ++q) {
      float v = a8[q] * 0.25f + b1[j0 + q];
      v = fmaxf(v, 0.0f);
      if (!isfinite(v)) v = 0.0f;
      h1[(size_t)(nb + m) * 32 + j0 + q] = v;
      ot[m * 33 + j0 + q] = v;
    }
    __syncthreads();
#pragma unroll
    for (int q = 0; q < 2; ++q) {
      int t = q * 256 + tid;
      int s = t & 7, row = t >> 3;
      const float* vp = prep2 + (s & 3) * 128 + ((s >= 4) ? 512 : 0);
      float p = 0.0f;
#pragma unroll
      for (int c = 0; c < 32; ++c) p += ot[row * 33 + c] * vp[c];
      int n = nb + row;
      if (s < 4) ssrcB[(size_t)n * 4 + s] = p;
      else       sdstB[(size_t)n * 4 + (s - 4)] = p;
    }
  }
  gridbar(bar, 3 * GRID);

  // ===== P3: agg2 (LDS only) + MFMA gemm2 + layer-3 scores (-> A buffers). 512 units. =====
  {
    _Float16* As16 = (_Float16*)LB;             // [64][136]
    _Float16* Bs16 = (_Float16*)(LB + 17408);   // [128][64]
    float* se_ = (float*)(LB + 33792);
    const int nb = blockIdx.x * 64;
    for (int j = tid; j < 40; j += 256) se_[j] = (j < 36) ? prep2[1024 + j] : 0.0f;
    __syncthreads();
    for (int g = 0; g < 16; ++g) {
      int nl = wv * 16 + g, n = nb + nl;
      int kd = min(cnt[n], CSR_CAP);
      int o0 = n * CSR_CAP;
      const float* sdp = sdstB + (size_t)n * 4;
      float sd0 = sdp[0], sd1 = sdp[1], sd2 = sdp[2], sd3 = sdp[3];
      float a0 = -1e30f, a1 = -1e30f, a2 = -1e30f, a3 = -1e30f;
      float m0 = -1e30f, m1 = -1e30f, m2 = -1e30f, m3 = -1e30f;
      float z0 = 0, z1 = 0, z2 = 0, z3 = 0;
      int sx = 0;
      if (lane < kd) {
        int ent = csr[o0 + lane];
        sx = ent & (N_NODES - 1);
        int tt = (ent >> 16) & 15;
        const float4 sv = *reinterpret_cast<const float4*>(ssrcB + (size_t)sx * 4);
        a0 = lrelu(sv.x + sd0 + se_[tt * 4 + 0]);
        a1 = lrelu(sv.y + sd1 + se_[tt * 4 + 1]);
        a2 = lrelu(sv.z + sd2 + se_[tt * 4 + 2]);
        a3 = lrelu(sv.w + sd3 + se_[tt * 4 + 3]);
        m0 = a0; m1 = a1; m2 = a2; m3 = a3;
        z0 = 1; z1 = 1; z2 = 1; z3 = 1;
      }
#pragma unroll
      for (int off = 32; off >= 1; off >>= 1) {
        osm_comb(m0, z0, off); osm_comb(m1, z1, off);
        osm_comb(m2, z2, off); osm_comb(m3, z3, off);
      }
      float r0 = (z0 > 0.0f) ? 1.0f / z0 : 0.0f;
      float r1 = (z1 > 0.0f) ? 1.0f / z1 : 0.0f;
      float r2 = (z2 > 0.0f) ? 1.0f / z2 : 0.0f;
      float r3 = (z3 > 0.0f) ? 1.0f / z3 : 0.0f;
      float w0 = 0, w1 = 0, w2 = 0, w3 = 0;
      if (lane < kd) {
        w0 = __expf(a0 - m0) * r0; w1 = __expf(a1 - m1) * r1;
        w2 = __expf(a2 - m2) * r2; w3 = __expf(a3 - m3) * r3;
      }
      float ac0 = 0.0f, ac1 = 0.0f;
      for (int e = 0; e < kd; ++e) {
        int se2 = __shfl(sx, e, 64);
        float u0 = __shfl(w0, e, 64), u1 = __shfl(w1, e, 64);
        float u2 = __shfl(w2, e, 64), u3 = __shfl(w3, e, 64);
        float v = h1[(size_t)se2 * 32 + (lane & 31)];
        bool hi = lane >= 32;
        float wa = hi ? u1 : u0;
        float wb = hi ? u3 : u2;
        ac0 += wa * v; ac1 += wb * v;
      }
      As16[nl * 136 + lane]      = (_Float16)ac0;
      As16[nl * 136 + 64 + lane] = (_Float16)ac1;
    }
    __syncthreads();
    // gemm2: M=64 (LDS A, full K=128), N=128, staged B per K-half
    float bv[4];
#pragma unroll
    for (int fj = 0; fj < 4; ++fj) bv[fj] = b2[wn + fj * 16 + l16];
    f32x4 acc[2][4] = {};
    for (int kb = 0; kb < 128; kb += 64) {
      __syncthreads();
#pragma unroll
      for (int i = 0; i < 4; ++i) {
        int q = wv * 4 + i, r = q * 8 + srow;
        gload16(reinterpret_cast<const char*>(w2t) + (size_t)r * 256 + kb * 2 + scolB,
                &Bs16[q * 512]);
      }
      __syncthreads();
#pragma unroll
      for (int h = 0; h < 2; ++h) {
        f16x8 af[2], bf[4];
#pragma unroll
        for (int f = 0; f < 2; ++f)
          af[f] = *reinterpret_cast<const f16x8*>(&As16[(wm + f * 16 + l16) * 136 + kb + h * 32 + quad * 8]);
#pragma unroll
        for (int f = 0; f < 4; ++f)
          bf[f] = *reinterpret_cast<const f16x8*>(&Bs16[(wn + f * 16 + l16) * 64 + h * 32 + quad * 8]);
#pragma unroll
        for (int fi = 0; fi < 2; ++fi)
#pragma unroll
          for (int fj = 0; fj < 4; ++fj)
            acc[fi][fj] = __builtin_amdgcn_mfma_f32_16x16x32_f16(af[fi], bf[fj], acc[fi][fj], 0, 0, 0);
      }
    }
    __syncthreads();                     // all MFMA reads of As16 done
    _Float16* ot16 = As16;               // reuse as [64][136]
#pragma unroll
    for (int fi = 0; fi < 2; ++fi)
#pragma unroll
      for (int reg = 0; reg < 4; ++reg) {
        int ml = wm + fi * 16 + quad * 4 + reg;
#pragma unroll
        for (int fj = 0; fj < 4; ++fj) {
          int j = wn + fj * 16 + l16;
          float v = acc[fi][fj][reg] * 0.25f + bv[fj];
          v = fmaxf(v, 0.0f);
          if (!isfinite(v)) v = 0.0f;
          _Float16 hv = (_Float16)v;
          h2[(size_t)(nb + ml) * 128 + j] = hv;
          ot16[ml * 136 + j] = hv;
        }
      }
    __syncthreads();
#pragma unroll
    for (int q = 0; q < 2; ++q) {
      int t = q * 256 + tid;
      int s = t & 7, row = t >> 3;
      const float* vp = prep3 + (s & 3) * 128 + ((s >= 4) ? 512 : 0);
      float p = 0.0f;
#pragma unroll
      for (int c0 = 0; c0 < 128; c0 += 8) {
        f16x8 hv = *reinterpret_cast<const f16x8*>(&ot16[row * 136 + c0]);
        float4 q0 = *reinterpret_cast<const float4*>(vp + c0);
        float4 q1 = *reinterpret_cast<const float4*>(vp + c0 + 4);
        p += (float)hv[0] * q0.x + (float)hv[1] * q0.y + (float)hv[2] * q0.z + (float)hv[3] * q0.w
           + (float)hv[4] * q1.x + (float)hv[5] * q1.y + (float)hv[6] * q1.z + (float)hv[7] * q1.w;
      }
      int n = nb + row;
      if (s < 4) ssrcA[(size_t)n * 4 + s] = p;
      else       sdstA[(size_t)n * 4 + (s - 4)] = p;
    }
  }
  gridbar(bar, 4 * GRID);

  // ===== P4: agg3 -> global (8192 units of 4 nodes) =====
  {
    float* se_ = (float*)(LB + 33792);
    for (int j = tid; j < 40; j += 256) se_[j] = (j < 36) ? prep3[1024 + j] : 0.0f;
    __syncthreads();
    for (int vb = blockIdx.x; vb < 8192; vb += GRID) {
      int n = vb * 4 + wv;
      int kd = min(cnt[n], CSR_CAP);
      int o0 = n * CSR_CAP;
      const float* sdp = sdstA + (size_t)n * 4;
      float sd0 = sdp[0], sd1 = sdp[1], sd2 = sdp[2], sd3 = sdp[3];
      float a0 = -1e30f, a1 = -1e30f, a2 = -1e30f, a3 = -1e30f;
      float m0 = -1e30f, m1 = -1e30f, m2 = -1e30f, m3 = -1e30f;
      float z0 = 0, z1 = 0, z2 = 0, z3 = 0;
      int sx = 0;
      if (lane < kd) {
        int ent = csr[o0 + lane];
        sx = ent & (N_NODES - 1);
        int tt = (ent >> 16) & 15;
        const float4 sv = *reinterpret_cast<const float4*>(ssrcA + (size_t)sx * 4);
        a0 = lrelu(sv.x + sd0 + se_[tt * 4 + 0]);
        a1 = lrelu(sv.y + sd1 + se_[tt * 4 + 1]);
        a2 = lrelu(sv.z + sd2 + se_[tt * 4 + 2]);
        a3 = lrelu(sv.w + sd3 + se_[tt * 4 + 3]);
        m0 = a0; m1 = a1; m2 = a2; m3 = a3;
        z0 = 1; z1 = 1; z2 = 1; z3 = 1;
      }
#pragma unroll
      for (int off = 32; off >= 1; off >>= 1) {
        osm_comb(m0, z0, off); osm_comb(m1, z1, off);
        osm_comb(m2, z2, off); osm_comb(m3, z3, off);
      }
      float r0 = (z0 > 0.0f) ? 1.0f / z0 : 0.0f;
      float r1 = (z1 > 0.0f) ? 1.0f / z1 : 0.0f;
      float r2 = (z2 > 0.0f) ? 1.0f / z2 : 0.0f;
      float r3 = (z3 > 0.0f) ? 1.0f / z3 : 0.0f;
      float w0 = 0, w1 = 0, w2 = 0, w3 = 0;
      if (lane < kd) {
        w0 = __expf(a0 - m0) * r0; w1 = __expf(a1 - m1) * r1;
        w2 = __expf(a2 - m2) * r2; w3 = __expf(a3 - m3) * r3;
      }
      float acc[8] = {};
      for (int e = 0; e < kd; ++e) {
        int se2 = __shfl(sx, e, 64);
        float u0 = __shfl(w0, e, 64), u1 = __shfl(w1, e, 64);
        float u2 = __shfl(w2, e, 64), u3 = __shfl(w3, e, 64);
        unsigned int ru = *reinterpret_cast<const unsigned int*>(
            reinterpret_cast<const char*>(h2) + (size_t)se2 * 256 + 4 * lane);
        union { unsigned int u; _Float16 hh[2]; } cv; cv.u = ru;
        float v0 = (float)cv.hh[0], v1 = (float)cv.hh[1];
        acc[0] += u0 * v0; acc[1] += u0 * v1;
        acc[2] += u1 * v0; acc[3] += u1 * v1;
        acc[4] += u2 * v0; acc[5] += u2 * v1;
        acc[6] += u3 * v0; acc[7] += u3 * v1;
      }
      _Float16* ar = agg3 + (size_t)n * 512;
#pragma unroll
      for (int h = 0; h < 4; ++h) {
        union { unsigned int u; _Float16 hh[2]; } ov;
        ov.hh[0] = (_Float16)acc[2 * h]; ov.hh[1] = (_Float16)acc[2 * h + 1];
        *reinterpret_cast<unsigned int*>(ar + h * 128 + 2 * lane) = ov.u;
      }
    }
  }
  gridbar(bar, 5 * GRID);

  // ===== P5: gemm3 (M=64 x N=128 units x 2048), fp32 out =====
  {
    _Float16* As16 = (_Float16*)LB;            // [64][64]
    _Float16* Bs16 = (_Float16*)(LB + 8192);   // [128][64]
    for (int vb = blockIdx.x; vb < 2048; vb += GRID) {
      const int ct = vb & 3, rt = vb >> 2;
      const int mb = rt * 64, jb = ct * 128;
      float bv[4];
#pragma unroll
      for (int fj = 0; fj < 4; ++fj) bv[fj] = b3[jb + wn + fj * 16 + l16];
      f32x4 acc[2][4] = {};
      for (int kb = 0; kb < 512; kb += 64) {
        __syncthreads();
#pragma unroll
        for (int i = 0; i < 2; ++i) {
          int q = wv * 2 + i, r = q * 8 + srow;
          gload16(reinterpret_cast<const char*>(agg3) + (size_t)(mb + r) * 1024 + kb * 2 + scolB,
                  &As16[q * 512]);
        }
#pragma unroll
        for (int i = 0; i < 4; ++i) {
          int q = wv * 4 + i, r = q * 8 + srow;
          gload16(reinterpret_cast<const char*>(w3t) + (size_t)(jb + r) * 1024 + kb * 2 + scolB,
                  &Bs16[q * 512]);
        }
        __syncthreads();
#pragma unroll
        for (int h = 0; h < 2; ++h) {
          f16x8 af[2], bf[4];
#pragma unroll
          for (int f = 0; f < 2; ++f)
            af[f] = *reinterpret_cast<const f16x8*>(&As16[(wm + f * 16 + l16) * 64 + h * 32 + quad * 8]);
#pragma unroll
          for (int f = 0; f < 4; ++f)
            bf[f] = *reinterpret_cast<const f16x8*>(&Bs16[(wn + f * 16 + l16) * 64 + h * 32 + quad * 8]);
#pragma unroll
          for (int fi = 0; fi < 2; ++fi)
#pragma unroll
            for (int fj = 0; fj < 4; ++fj)
              acc[fi][fj] = __builtin_amdgcn_mfma_f32_16x16x32_f16(af[fi], bf[fj], acc[fi][fj], 0, 0, 0);
        }
      }
#pragma unroll
      for (int fi = 0; fi < 2; ++fi)
#pragma unroll
        for (int reg = 0; reg < 4; ++reg) {
          int m = mb + wm + fi * 16 + quad * 4 + reg;
#pragma unroll
          for (int fj = 0; fj < 4; ++fj) {
            int j = jb + wn + fj * 16 + l16;
            float v = acc[fi][fj][reg] * 0.25f + bv[fj];
            if (!isfinite(v)) v = 0.0f;
            dout[(size_t)m * 512 + j] = v;
          }
        }
    }
  }
}

// ---------- launch ----------
extern "C" void kernel_launch(void* const* d_in, const int* in_sizes, int n_in,
                              void* d_out, int out_size, void* d_ws, size_t ws_size,
                              hipStream_t stream) {
  (void)in_sizes; (void)n_in; (void)out_size; (void)ws_size;
  const float* x   = (const float*)d_in[0];
  const int*   ei  = (const int*)d_in[1];
  const float* W1  = (const float*)d_in[2];
  const float* We1 = (const float*)d_in[3];
  const float* as1 = (const float*)d_in[4];
  const float* ad1 = (const float*)d_in[5];
  const float* ae1 = (const float*)d_in[6];
  const float* b1  = (const float*)d_in[7];
  const float* W2  = (const float*)d_in[8];
  const float* We2 = (const float*)d_in[9];
  const float* as2 = (const float*)d_in[10];
  const float* ad2 = (const float*)d_in[11];
  const float* ae2 = (const float*)d_in[12];
  const float* b2  = (const float*)d_in[13];
  const float* W3  = (const float*)d_in[14];
  const float* We3 = (const float*)d_in[15];
  const float* as3 = (const float*)d_in[16];
  const float* ad3 = (const float*)d_in[17];
  const float* ae3 = (const float*)d_in[18];
  const float* b3  = (const float*)d_in[19];

  // workspace layout (256B-aligned)
  char* p = (char*)d_ws;
  int* cnt       = (int*)(p + 0);              // 131072   [N]
  int* csr       = (int*)(p + 131072);         // 8388608  [N][64]
  float* ssrcA   = (float*)(p + 8519680);      // 524288
  float* sdstA   = (float*)(p + 9043968);      // 524288
  float* ssrcB   = (float*)(p + 9568256);      // 524288
  float* sdstB   = (float*)(p + 10092544);     // 524288
  float* prep1   = (float*)(p + 10616832);     // 4608
  float* prep2   = (float*)(p + 10621440);     // 4608
  float* prep3   = (float*)(p + 10626048);     // 4608
  float* h1      = (float*)(p + 10630656);     // 4194304  [N][32] f32
  _Float16* h2   = (_Float16*)(p + 14824960);  // 8388608  [N][128] f16
  _Float16* agg3 = (_Float16*)(p + 23213568);  // 33554432 [N][512] f16
  _Float16* w2t  = (_Float16*)(p + 56768000);  // 32768    Bt2[128][128]
  _Float16* w3t  = (_Float16*)(p + 56800768);  // 524288   Bt3[512][512]
  int* bar       = (int*)(p + 57325056);       // 256
  // end: 57325312 B

  hipMemsetAsync(bar, 0, 256, stream);
  k_mega<<<GRID, 256, 0, stream>>>(x, ei,
                                   W1, We1, as1, ad1, ae1, b1,
                                   W2, We2, as2, ad2, ae2, b2,
                                   W3, We3, as3, ad3, ae3, b3,
                                   cnt, csr, ssrcA, sdstA, ssrcB, sdstB,
                                   prep1, prep2, prep3, h1, h2, agg3, w2t, w3t,
                                   (float*)d_out, bar);
}

// Round 4
// 305.585 us; speedup vs baseline: 2.9373x; 2.9373x over previous
//
#include <hip/hip_runtime.h>
#include <hip/hip_bf16.h>
#include <math.h>

// Problem constants (NodeEncoder: 3-layer GAT on chess graph)
#define N_NODES 32768
#define E_PER   16384
#define T_TYPES 8
#define E_TYPED (T_TYPES * E_PER)      // 131072
#define E_TOT   (E_TYPED + N_NODES)    // 163840 (with self loops)
#define NEG_SLOPE 0.2f
#define CSR_CAP 64                     // fixed bucket capacity per node (P(deg>64) ~ 1e-50)

typedef _Float16 f16x8 __attribute__((ext_vector_type(8)));
typedef float f32x4 __attribute__((ext_vector_type(4)));

// ---------- helpers ----------
__device__ __forceinline__ float tof(float v) { return v; }
__device__ __forceinline__ float tof(_Float16 v) { return (float)v; }
__device__ __forceinline__ float lrelu(float a) { return a > 0.0f ? a : NEG_SLOPE * a; }

__device__ __forceinline__ void osm_comb(float& m, float& z, int off) {
  float om = __shfl_xor(m, off, 64);
  float oz = __shfl_xor(z, off, 64);
  float nm = fmaxf(m, om);
  z = z * __expf(m - nm) + oz * __expf(om - nm);
  m = nm;
}

// async global->LDS, 16B per lane; lds base must be wave-uniform (dest = base + lane*16)
__device__ __forceinline__ void gload16(const void* g, void* l) {
  __builtin_amdgcn_global_load_lds(
      (const __attribute__((address_space(1))) void*)g,
      (__attribute__((address_space(3))) void*)l,
      16, 0, 0);
}

// ===================================================================
// k_weights: fused weight-only preprocessing (all 3 layers) + cnt zero
//   prep layout (floats): [0..511] v_src[h*128+i], [512..1023] v_dst[h*128+i],
//                         [1024..1059] s_edge[t*4+h], t=0..8 (8 = self loop)
// ===================================================================
__device__ void prep_blk(int b, const float* __restrict__ W, const float* __restrict__ We,
                         const float* __restrict__ asrc, const float* __restrict__ adst,
                         const float* __restrict__ aedge, float* __restrict__ prep,
                         int din, int dout) {
  int task = b * 4 + (threadIdx.x >> 6);
  int lane = threadIdx.x & 63;
  int hd = 4 * din;
  float s = 0.0f;
  if (task < 2 * hd) {
    int k = (task < hd) ? task : task - hd;
    int h = k / din, i = k % din;
    const float* a = (task < hd) ? asrc : adst;
    for (int c = lane; c < dout; c += 64)
      s += W[(size_t)i * 4 * dout + h * dout + c] * a[h * dout + c];
#pragma unroll
    for (int off = 32; off >= 1; off >>= 1) s += __shfl_xor(s, off, 64);
    if (lane == 0) prep[((task < hd) ? 0 : 512) + h * 128 + i] = s;
  } else if (task < 2 * hd + 32) {
    int k = task - 2 * hd; int t = k >> 2, h = k & 3;
    for (int c = lane; c < dout; c += 64)
      s += We[(size_t)t * 4 * dout + h * dout + c] * aedge[h * dout + c];
#pragma unroll
    for (int off = 32; off >= 1; off >>= 1) s += __shfl_xor(s, off, 64);
    if (lane == 0) prep[1024 + t * 4 + h] = s;
  } else if (task < 2 * hd + 36) {
    int h = task - 2 * hd - 32;
    for (int t = 0; t < 8; ++t)
      for (int c = lane; c < dout; c += 64)
        s += We[(size_t)t * 4 * dout + h * dout + c] * aedge[h * dout + c];
#pragma unroll
    for (int off = 32; off >= 1; off >>= 1) s += __shfl_xor(s, off, 64);
    if (lane == 0) prep[1024 + 32 + h] = s * 0.125f;   // loop edge attr = mean one-hot
  }
}

// W -> Bt[j][k] fp16 (k = h*din+i), one 64x64 transpose tile
__device__ void wt_blk(int jt, int kt, const float* __restrict__ W,
                       _Float16* __restrict__ Bt, int din, int dout) {
  __shared__ float Tt[64][65];
  int jb = jt * 64, kb = kt * 64;
  int KK = 4 * din;
  int tx = threadIdx.x & 63, ty4 = threadIdx.x >> 6;
  for (int r0 = 0; r0 < 64; r0 += 4) {
    int r = r0 + ty4;
    int k = kb + r, h = k / din, i = k % din;
    Tt[r][tx] = W[(size_t)i * 4 * dout + h * dout + jb + tx];    // coalesced in j
  }
  __syncthreads();
  for (int r0 = 0; r0 < 64; r0 += 4) {
    int r = r0 + ty4;                                            // local j
    Bt[(size_t)(jb + r) * KK + kb + tx] = (_Float16)Tt[tx][r];   // coalesced in k
  }
}

#define NB_P1 41    // 164 tasks / 4 waves
#define NB_P2 73    // 292 tasks
#define NB_P3 265   // 1060 tasks
#define NB_W2 4     // 2x2 tiles
#define NB_W3 64    // 8x8 tiles
#define NB_Z  32    // 32768 ints (cnt) as int4
#define NB_WEIGHTS (NB_P1 + NB_P2 + NB_P3 + NB_W2 + NB_W3 + NB_Z)  // 479

__global__ __launch_bounds__(256) void k_weights(
    const float* __restrict__ W1, const float* __restrict__ We1,
    const float* __restrict__ as1, const float* __restrict__ ad1, const float* __restrict__ ae1,
    const float* __restrict__ W2, const float* __restrict__ We2,
    const float* __restrict__ as2, const float* __restrict__ ad2, const float* __restrict__ ae2,
    const float* __restrict__ W3, const float* __restrict__ We3,
    const float* __restrict__ as3, const float* __restrict__ ad3, const float* __restrict__ ae3,
    float* __restrict__ prep1, float* __restrict__ prep2, float* __restrict__ prep3,
    _Float16* __restrict__ w2t, _Float16* __restrict__ w3t, int* __restrict__ cnt) {
  int b = blockIdx.x;
  if (b < NB_P1) { prep_blk(b, W1, We1, as1, ad1, ae1, prep1, 16, 32); return; }
  b -= NB_P1;
  if (b < NB_P2) { prep_blk(b, W2, We2, as2, ad2, ae2, prep2, 32, 128); return; }
  b -= NB_P2;
  if (b < NB_P3) { prep_blk(b, W3, We3, as3, ad3, ae3, prep3, 128, 512); return; }
  b -= NB_P3;
  if (b < NB_W2) { wt_blk(b & 1, b >> 1, W2, w2t, 32, 128); return; }
  b -= NB_W2;
  if (b < NB_W3) { wt_blk(b & 7, b >> 3, W3, w3t, 128, 512); return; }
  b -= NB_W3;
  // zero cnt (degree counters for bucket CSR)
  int4 z; z.x = z.y = z.z = z.w = 0;
  reinterpret_cast<int4*>(cnt)[b * 256 + threadIdx.x] = z;
}

// ---------- bucket CSR fill fused with layer-1 scores ----------
__global__ __launch_bounds__(256) void k_fill_s1(const int* __restrict__ ei, int* __restrict__ cnt,
                                                 int* __restrict__ csr,
                                                 const float* __restrict__ x,
                                                 const float* __restrict__ prep1,
                                                 float* __restrict__ s_src,
                                                 float* __restrict__ s_dst) {
  int b = blockIdx.x;
  if (b < E_TOT / 256) {
    int e = b * 256 + threadIdx.x;
    int src, dst, t;
    if (e < E_TYPED) { t = e >> 14; int j = e & (E_PER - 1); src = ei[2 * t * E_PER + j]; dst = ei[(2 * t + 1) * E_PER + j]; }
    else { src = dst = e - E_TYPED; t = 8; }
    dst &= (N_NODES - 1);
    int pos = atomicAdd(cnt + dst, 1);
    if (pos < CSR_CAP)
      csr[dst * CSR_CAP + pos] = (src & (N_NODES - 1)) | (t << 16);
    return;
  }
  // ---- scores, layer 1 (DIN=16, fp32 input) ----
  __shared__ float vv[128];
  int tid = threadIdx.x;
  for (int j = tid; j < 128; j += 256) {
    int s = j / 16, i = j % 16;
    vv[j] = prep1[(s & 3) * 128 + i + ((s >= 4) ? 512 : 0)];
  }
  __syncthreads();
  int lane = tid & 63, wv = tid >> 6;
  int n = (b - E_TOT / 256) * 4 + wv;
  const float* row = x + (size_t)n * 16;
  float p0 = 0, p1 = 0, p2 = 0, p3 = 0, p4 = 0, p5 = 0, p6 = 0, p7 = 0;
  for (int c = lane; c < 16; c += 64) {
    float v = row[c];
    p0 += v * vv[0 * 16 + c]; p1 += v * vv[1 * 16 + c];
    p2 += v * vv[2 * 16 + c]; p3 += v * vv[3 * 16 + c];
    p4 += v * vv[4 * 16 + c]; p5 += v * vv[5 * 16 + c];
    p6 += v * vv[6 * 16 + c]; p7 += v * vv[7 * 16 + c];
  }
#pragma unroll
  for (int off = 32; off >= 1; off >>= 1) {
    p0 += __shfl_xor(p0, off, 64); p1 += __shfl_xor(p1, off, 64);
    p2 += __shfl_xor(p2, off, 64); p3 += __shfl_xor(p3, off, 64);
    p4 += __shfl_xor(p4, off, 64); p5 += __shfl_xor(p5, off, 64);
    p6 += __shfl_xor(p6, off, 64); p7 += __shfl_xor(p7, off, 64);
  }
  if (lane == 0) {
    float* a = s_src + (size_t)n * 4; a[0] = p0; a[1] = p1; a[2] = p2; a[3] = p3;
    float* bq = s_dst + (size_t)n * 4; bq[0] = p4; bq[1] = p5; bq[2] = p6; bq[3] = p7;
  }
}

// ---------- softmax + input-space aggregation (wave per dst node) ----------
// Single pass: kd <= 64, so one edge per lane; butterfly online-softmax; weights in-register.
template <typename TI, int DIN, typename TO>
__global__ __launch_bounds__(256) void k_attn_agg(const TI* __restrict__ hin,
                                                  const int* __restrict__ csr,
                                                  const int* __restrict__ cnt,
                                                  const float* __restrict__ prep,
                                                  const float* __restrict__ s_src,
                                                  const float* __restrict__ s_dst,
                                                  TO* __restrict__ agg) {
  constexpr int ACC = (4 * DIN) / 64;   // 1 / 2 / 8
  __shared__ float se[68];              // 36 used, zero-padded
  int tid = threadIdx.x, lane = tid & 63, wv = tid >> 6;
  for (int j = tid; j < 68; j += 256) se[j] = (j < 36) ? prep[1024 + j] : 0.0f;
  __syncthreads();
  int n = blockIdx.x * 4 + wv;
  int kd = min(max(cnt[n], 0), CSR_CAP);
  int o0 = n * CSR_CAP;
  const float* sdp = s_dst + (size_t)n * 4;
  float sd0 = sdp[0], sd1 = sdp[1], sd2 = sdp[2], sd3 = sdp[3];

  float a0 = -1e30f, a1 = -1e30f, a2 = -1e30f, a3 = -1e30f;
  float m0 = -1e30f, m1 = -1e30f, m2 = -1e30f, m3 = -1e30f;
  float z0 = 0, z1 = 0, z2 = 0, z3 = 0;
  int sx = 0;
  if (lane < kd) {
    int ent = csr[o0 + lane];
    sx = ent & (N_NODES - 1);
    int tt = (ent >> 16) & 15;
    const float4 sv = *reinterpret_cast<const float4*>(s_src + (size_t)sx * 4);
    a0 = lrelu(sv.x + sd0 + se[tt * 4 + 0]);
    a1 = lrelu(sv.y + sd1 + se[tt * 4 + 1]);
    a2 = lrelu(sv.z + sd2 + se[tt * 4 + 2]);
    a3 = lrelu(sv.w + sd3 + se[tt * 4 + 3]);
    m0 = a0; m1 = a1; m2 = a2; m3 = a3;
    z0 = 1; z1 = 1; z2 = 1; z3 = 1;
  }
#pragma unroll
  for (int off = 32; off >= 1; off >>= 1) {
    osm_comb(m0, z0, off); osm_comb(m1, z1, off);
    osm_comb(m2, z2, off); osm_comb(m3, z3, off);
  }
  float r0 = (z0 > 0.0f) ? 1.0f / z0 : 0.0f;
  float r1 = (z1 > 0.0f) ? 1.0f / z1 : 0.0f;
  float r2 = (z2 > 0.0f) ? 1.0f / z2 : 0.0f;
  float r3 = (z3 > 0.0f) ? 1.0f / z3 : 0.0f;
  float w0 = 0, w1 = 0, w2 = 0, w3 = 0;
  if (lane < kd) {
    w0 = __expf(a0 - m0) * r0; w1 = __expf(a1 - m1) * r1;
    w2 = __expf(a2 - m2) * r2; w3 = __expf(a3 - m3) * r3;
  }

  float acc[ACC];
#pragma unroll
  for (int q = 0; q < ACC; ++q) acc[q] = 0.0f;

  int e = 0;
  for (; e + 2 <= kd; e += 2) {
    int sA = __shfl(sx, e, 64), sB = __shfl(sx, e + 1, 64);
    float uA0 = __shfl(w0, e, 64), uA1 = __shfl(w1, e, 64);
    float uA2 = __shfl(w2, e, 64), uA3 = __shfl(w3, e, 64);
    float uB0 = __shfl(w0, e + 1, 64), uB1 = __shfl(w1, e + 1, 64);
    float uB2 = __shfl(w2, e + 1, 64), uB3 = __shfl(w3, e + 1, 64);
    if constexpr (DIN == 128) {
      unsigned int rA = *reinterpret_cast<const unsigned int*>(
          reinterpret_cast<const char*>(hin) + (size_t)sA * 256 + 4 * lane);
      unsigned int rB = *reinterpret_cast<const unsigned int*>(
          reinterpret_cast<const char*>(hin) + (size_t)sB * 256 + 4 * lane);
      union { unsigned int u; _Float16 h[2]; } cA, cB; cA.u = rA; cB.u = rB;
      float vA0 = (float)cA.h[0], vA1 = (float)cA.h[1];
      float vB0 = (float)cB.h[0], vB1 = (float)cB.h[1];
      acc[0] += uA0 * vA0 + uB0 * vB0; acc[1] += uA0 * vA1 + uB0 * vB1;
      acc[2] += uA1 * vA0 + uB1 * vB0; acc[3] += uA1 * vA1 + uB1 * vB1;
      acc[4] += uA2 * vA0 + uB2 * vB0; acc[5] += uA2 * vA1 + uB2 * vB1;
      acc[6] += uA3 * vA0 + uB3 * vB0; acc[7] += uA3 * vA1 + uB3 * vB1;
    } else if constexpr (DIN == 32) {
      float vA = tof(hin[(size_t)sA * 32 + (lane & 31)]);
      float vB = tof(hin[(size_t)sB * 32 + (lane & 31)]);
      bool hi = lane >= 32;
      float wAa = hi ? uA1 : uA0, wAb = hi ? uA3 : uA2;
      float wBa = hi ? uB1 : uB0, wBb = hi ? uB3 : uB2;
      acc[0] += wAa * vA + wBa * vB; acc[1] += wAb * vA + wBb * vB;
    } else {
      float vA = tof(hin[(size_t)sA * 16 + (lane & 15)]);
      float vB = tof(hin[(size_t)sB * 16 + (lane & 15)]);
      int hh = lane >> 4;
      float wAa = (hh == 0) ? uA0 : (hh == 1) ? uA1 : (hh == 2) ? uA2 : uA3;
      float wBa = (hh == 0) ? uB0 : (hh == 1) ? uB1 : (hh == 2) ? uB2 : uB3;
      acc[0] += wAa * vA + wBa * vB;
    }
  }
  if (e < kd) {
    int sA = __shfl(sx, e, 64);
    float uA0 = __shfl(w0, e, 64), uA1 = __shfl(w1, e, 64);
    float uA2 = __shfl(w2, e, 64), uA3 = __shfl(w3, e, 64);
    if constexpr (DIN == 128) {
      unsigned int rA = *reinterpret_cast<const unsigned int*>(
          reinterpret_cast<const char*>(hin) + (size_t)sA * 256 + 4 * lane);
      union { unsigned int u; _Float16 h[2]; } cA; cA.u = rA;
      float vA0 = (float)cA.h[0], vA1 = (float)cA.h[1];
      acc[0] += uA0 * vA0; acc[1] += uA0 * vA1;
      acc[2] += uA1 * vA0; acc[3] += uA1 * vA1;
      acc[4] += uA2 * vA0; acc[5] += uA2 * vA1;
      acc[6] += uA3 * vA0; acc[7] += uA3 * vA1;
    } else if constexpr (DIN == 32) {
      float vA = tof(hin[(size_t)sA * 32 + (lane & 31)]);
      bool hi = lane >= 32;
      float wAa = hi ? uA1 : uA0, wAb = hi ? uA3 : uA2;
      acc[0] += wAa * vA; acc[1] += wAb * vA;
    } else {
      float vA = tof(hin[(size_t)sA * 16 + (lane & 15)]);
      int hh = lane >> 4;
      float wAa = (hh == 0) ? uA0 : (hh == 1) ? uA1 : (hh == 2) ? uA2 : uA3;
      acc[0] += wAa * vA;
    }
  }

  TO* ar = agg + (size_t)n * (4 * DIN);
  if constexpr (DIN == 128) {
#pragma unroll
    for (int h = 0; h < 4; ++h) {
      ar[h * 128 + 2 * lane]     = (TO)acc[2 * h];
      ar[h * 128 + 2 * lane + 1] = (TO)acc[2 * h + 1];
    }
  } else if constexpr (DIN == 32) {
    ar[lane]      = (TO)acc[0];
    ar[64 + lane] = (TO)acc[1];
  } else {
    ar[lane] = (TO)acc[0];
  }
}

// ---------- layer 1 GEMM (fp32, K=64, DOUT=32) fused with layer-2 scores ----------
__global__ __launch_bounds__(128) void k_gemm1_s2(const float* __restrict__ A,
                                                  const float* __restrict__ W,
                                                  const float* __restrict__ bias,
                                                  const float* __restrict__ prep2,
                                                  float* __restrict__ out,
                                                  float* __restrict__ s_src,
                                                  float* __restrict__ s_dst) {
  constexpr int BM = 64, BN = 32, BK = 16, TM = 4, TN = 4, NT = 128;
  constexpr int K = 64, DIN = 16, DOUT = 32;
  constexpr int LDA = BM + 4;
  constexpr int LDB = BN + 4;
  __shared__ __align__(16) float As[BK * LDA];
  __shared__ __align__(16) float Bs[BK * LDB];
  __shared__ float ot[64][33];           // full output tile for scores epilogue
  const int tid = threadIdx.x;
  const int tx = tid % (BN / TN);
  const int ty = tid / (BN / TN);
  const int mb = blockIdx.y * BM;
  float acc[TM][TN] = {};
  constexpr int ITA = (BM * BK) / (NT * 4);   // 2
  constexpr int ITB = (BK * BN) / (NT * 4);   // 1
  for (int kb = 0; kb < K; kb += BK) {
#pragma unroll
    for (int it = 0; it < ITA; ++it) {
      int f = it * NT * 4 + tid * 4;
      int r = f / BK, c = f % BK;
      float4 u = *reinterpret_cast<const float4*>(A + (size_t)(mb + r) * K + kb + c);
      As[(c + 0) * LDA + r] = u.x;
      As[(c + 1) * LDA + r] = u.y;
      As[(c + 2) * LDA + r] = u.z;
      As[(c + 3) * LDA + r] = u.w;
    }
#pragma unroll
    for (int it = 0; it < ITB; ++it) {
      int f = it * NT * 4 + tid * 4;
      int kk = f / BN, jj = f % BN;
      int k = kb + kk; int h = k / DIN; int i = k % DIN;
      float4 u = *reinterpret_cast<const float4*>(W + (size_t)i * 4 * DOUT + h * DOUT + jj);
      Bs[kk * LDB + jj + 0] = u.x;
      Bs[kk * LDB + jj + 1] = u.y;
      Bs[kk * LDB + jj + 2] = u.z;
      Bs[kk * LDB + jj + 3] = u.w;
    }
    __syncthreads();
#pragma unroll
    for (int kk = 0; kk < BK; ++kk) {
      float a_[TM], b_[TN];
      float4 va = *reinterpret_cast<const float4*>(&As[kk * LDA + ty * TM]);
      a_[0] = va.x; a_[1] = va.y; a_[2] = va.z; a_[3] = va.w;
      float4 vb = *reinterpret_cast<const float4*>(&Bs[kk * LDB + tx * TN]);
      b_[0] = vb.x; b_[1] = vb.y; b_[2] = vb.z; b_[3] = vb.w;
#pragma unroll
      for (int ii = 0; ii < TM; ++ii)
#pragma unroll
        for (int jj = 0; jj < TN; ++jj)
          acc[ii][jj] = fmaf(a_[ii], b_[jj], acc[ii][jj]);
    }
    __syncthreads();
  }
#pragma unroll
  for (int ii = 0; ii < TM; ++ii) {
    int ml = ty * TM + ii;
#pragma unroll
    for (int jj = 0; jj < TN; ++jj) {
      int j = tx * TN + jj;
      float v = acc[ii][jj] * 0.25f + bias[j];
      v = fmaxf(v, 0.0f);                // layer-1 relu
      out[(size_t)(mb + ml) * DOUT + j] = v;
      ot[ml][j] = v;
    }
  }
  __syncthreads();
  // ---- scores for layer 2 (din=32) on these 64 rows ----
#pragma unroll
  for (int q = 0; q < 4; ++q) {
    int t = q * 128 + tid;               // 512 tasks
    int s = t & 7, row = t >> 3;
    const float* vp = prep2 + (s & 3) * 128 + ((s >= 4) ? 512 : 0);
    float p = 0.0f;
#pragma unroll
    for (int c = 0; c < 32; ++c) p += ot[row][c] * vp[c];
    int n = mb + row;
    if (s < 4) s_src[(size_t)n * 4 + s] = p;
    else       s_dst[(size_t)n * 4 + (s - 4)] = p;
  }
}

// ---------- layer 2 MFMA GEMM (K=128, DOUT=128, relu) fused with layer-3 scores ----------
// Staging via global_load_lds width-16, linear LDS [128][64] halves.
__global__ __launch_bounds__(256) void k_gemm2_s3(const _Float16* __restrict__ A,
                                                  const _Float16* __restrict__ Bt,
                                                  const float* __restrict__ bias,
                                                  const float* __restrict__ prep3,
                                                  _Float16* __restrict__ out,
                                                  float* __restrict__ s_src,
                                                  float* __restrict__ s_dst) {
  constexpr int K = 128, DOUT = 128, BM = 128, BK = 64;
  __shared__ _Float16 smem[128 * 136];            // As[0..8191] | Bs[8192..16383]; reused as ot[128][136]
  _Float16* As = smem;
  _Float16* Bs = smem + 8192;
  const int tid = threadIdx.x;
  const int lane = tid & 63, wv = tid >> 6;
  const int quad = lane >> 4, l16 = lane & 15;
  const int wm = (wv >> 1) * 64, wn = (wv & 1) * 64;
  const int mb = blockIdx.y * BM;
  const int srow = lane >> 3;                     // 0..7
  const int scolB = (lane & 7) * 16;              // 0..112 bytes

  f32x4 acc[4][4] = {};
  float bv[4];
#pragma unroll
  for (int fj = 0; fj < 4; ++fj) bv[fj] = bias[wn + fj * 16 + l16];

  for (int kb = 0; kb < K; kb += BK) {
    __syncthreads();
#pragma unroll
    for (int i = 0; i < 4; ++i) {
      int q = wv * 4 + i;                         // wave-load index 0..15
      int r = q * 8 + srow;                       // tile row 0..127
      gload16(reinterpret_cast<const char*>(A) + (size_t)(mb + r) * 256 + kb * 2 + scolB,
              &As[q * 512]);
      gload16(reinterpret_cast<const char*>(Bt) + (size_t)r * 256 + kb * 2 + scolB,
              &Bs[q * 512]);
    }
    __syncthreads();
#pragma unroll
    for (int h = 0; h < 2; ++h) {
      f16x8 af[4], bf[4];
#pragma unroll
      for (int f = 0; f < 4; ++f) {
        af[f] = *reinterpret_cast<const f16x8*>(&As[(wm + f * 16 + l16) * 64 + h * 32 + quad * 8]);
        bf[f] = *reinterpret_cast<const f16x8*>(&Bs[(wn + f * 16 + l16) * 64 + h * 32 + quad * 8]);
      }
#pragma unroll
      for (int fi = 0; fi < 4; ++fi)
#pragma unroll
        for (int fj = 0; fj < 4; ++fj)
          acc[fi][fj] = __builtin_amdgcn_mfma_f32_16x16x32_f16(af[fi], bf[fj], acc[fi][fj], 0, 0, 0);
    }
  }
  __syncthreads();                          // all frag reads done before smem reuse
  _Float16* ot = smem;                      // [128][136]
#pragma unroll
  for (int fi = 0; fi < 4; ++fi)
#pragma unroll
    for (int reg = 0; reg < 4; ++reg) {
      int ml = wm + fi * 16 + quad * 4 + reg;
#pragma unroll
      for (int fj = 0; fj < 4; ++fj) {
        int j = wn + fj * 16 + l16;
        float v = acc[fi][fj][reg] * 0.25f + bv[fj];
        v = fmaxf(v, 0.0f);                 // layer-2 relu
        _Float16 hv = (_Float16)v;
        out[(size_t)(mb + ml) * DOUT + j] = hv;
        ot[ml * 136 + j] = hv;
      }
    }
  __syncthreads();
  // ---- scores for layer 3 (din=128) on these 128 rows ----
#pragma unroll
  for (int q = 0; q < 4; ++q) {
    int t = q * 256 + tid;                  // 1024 tasks
    int s = t & 7, row = t >> 3;
    const float* vp = prep3 + (s & 3) * 128 + ((s >= 4) ? 512 : 0);
    float p = 0.0f;
#pragma unroll
    for (int c0 = 0; c0 < 128; c0 += 8) {
      f16x8 hv = *reinterpret_cast<const f16x8*>(&ot[row * 136 + c0]);
      float4 a0 = *reinterpret_cast<const float4*>(vp + c0);
      float4 a1 = *reinterpret_cast<const float4*>(vp + c0 + 4);
      p += (float)hv[0] * a0.x + (float)hv[1] * a0.y + (float)hv[2] * a0.z + (float)hv[3] * a0.w
         + (float)hv[4] * a1.x + (float)hv[5] * a1.y + (float)hv[6] * a1.z + (float)hv[7] * a1.w;
    }
    int n = mb + row;
    if (s < 4) s_src[(size_t)n * 4 + s] = p;
    else       s_dst[(size_t)n * 4 + (s - 4)] = p;
  }
}

// ---------- layer 3 MFMA GEMM (K=512, DOUT=512, fp32 out, no relu) ----------
// Staging via global_load_lds width-16, linear LDS [128][64] halves.
template <int K, int DOUT, bool RELU, typename TO>
__global__ __launch_bounds__(256) void k_gemm_mfma64(const _Float16* __restrict__ A,
                                                     const _Float16* __restrict__ Bt,
                                                     const float* __restrict__ bias,
                                                     TO* __restrict__ out) {
  constexpr int BM = 128, BK = 64;
  __shared__ _Float16 As[128 * 64];
  __shared__ _Float16 Bs[128 * 64];
  const int tid = threadIdx.x;
  const int lane = tid & 63, wv = tid >> 6;
  const int quad = lane >> 4, l16 = lane & 15;
  const int wm = (wv >> 1) * 64, wn = (wv & 1) * 64;
  const int mb = blockIdx.y * BM, jb = blockIdx.x * BM;
  const int srow = lane >> 3;
  const int scolB = (lane & 7) * 16;
  constexpr int ROWB = K * 2;                     // global row stride in bytes

  f32x4 acc[4][4] = {};
  float bv[4];
#pragma unroll
  for (int fj = 0; fj < 4; ++fj) bv[fj] = bias[jb + wn + fj * 16 + l16];

  for (int kb = 0; kb < K; kb += BK) {
    __syncthreads();
#pragma unroll
    for (int i = 0; i < 4; ++i) {
      int q = wv * 4 + i;
      int r = q * 8 + srow;
      gload16(reinterpret_cast<const char*>(A) + (size_t)(mb + r) * ROWB + kb * 2 + scolB,
              &As[q * 512]);
      gload16(reinterpret_cast<const char*>(Bt) + (size_t)(jb + r) * ROWB + kb * 2 + scolB,
              &Bs[q * 512]);
    }
    __syncthreads();
#pragma unroll
    for (int h = 0; h < 2; ++h) {
      f16x8 af[4], bf[4];
#pragma unroll
      for (int f = 0; f < 4; ++f) {
        af[f] = *reinterpret_cast<const f16x8*>(&As[(wm + f * 16 + l16) * 64 + h * 32 + quad * 8]);
        bf[f] = *reinterpret_cast<const f16x8*>(&Bs[(wn + f * 16 + l16) * 64 + h * 32 + quad * 8]);
      }
#pragma unroll
      for (int fi = 0; fi < 4; ++fi)
#pragma unroll
        for (int fj = 0; fj < 4; ++fj)
          acc[fi][fj] = __builtin_amdgcn_mfma_f32_16x16x32_f16(af[fi], bf[fj], acc[fi][fj], 0, 0, 0);
    }
  }
#pragma unroll
  for (int fi = 0; fi < 4; ++fi)
#pragma unroll
    for (int reg = 0; reg < 4; ++reg) {
      int m = mb + wm + fi * 16 + quad * 4 + reg;
#pragma unroll
      for (int fj = 0; fj < 4; ++fj) {
        int j = jb + wn + fj * 16 + l16;
        float v = acc[fi][fj][reg] * 0.25f + bv[fj];
        if (RELU) v = fmaxf(v, 0.0f);
        out[(size_t)m * DOUT + j] = (TO)v;
      }
    }
}

// ---------- launch ----------
extern "C" void kernel_launch(void* const* d_in, const int* in_sizes, int n_in,
                              void* d_out, int out_size, void* d_ws, size_t ws_size,
                              hipStream_t stream) {
  (void)in_sizes; (void)n_in; (void)out_size; (void)ws_size;
  const float* x   = (const float*)d_in[0];
  const int*   ei  = (const int*)d_in[1];
  const float* W1  = (const float*)d_in[2];
  const float* We1 = (const float*)d_in[3];
  const float* as1 = (const float*)d_in[4];
  const float* ad1 = (const float*)d_in[5];
  const float* ae1 = (const float*)d_in[6];
  const float* b1  = (const float*)d_in[7];
  const float* W2  = (const float*)d_in[8];
  const float* We2 = (const float*)d_in[9];
  const float* as2 = (const float*)d_in[10];
  const float* ad2 = (const float*)d_in[11];
  const float* ae2 = (const float*)d_in[12];
  const float* b2  = (const float*)d_in[13];
  const float* W3  = (const float*)d_in[14];
  const float* We3 = (const float*)d_in[15];
  const float* as3 = (const float*)d_in[16];
  const float* ad3 = (const float*)d_in[17];
  const float* ae3 = (const float*)d_in[18];
  const float* b3  = (const float*)d_in[19];

  // workspace layout (256B-aligned offsets)
  char* p = (char*)d_ws;
  int* cnt       = (int*)(p + 0);              // 131072   [N]
  int* csr       = (int*)(p + 131072);         // 8388608  [N][64]
  float* ssrc    = (float*)(p + 8519680);      // 524288   [N][4]
  float* sdst    = (float*)(p + 9043968);      // 524288   [N][4]
  float* prep1   = (float*)(p + 9568256);      // 4608
  float* prep2   = (float*)(p + 9572864);      // 4608
  float* prep3   = (float*)(p + 9577472);      // 4608
  float* h1      = (float*)(p + 9582080);      // 4194304  [N][32] f32
  _Float16* h2   = (_Float16*)(p + 13776384);  // 8388608  [N][128] f16
  float* agg1    = (float*)(p + 22164992);     // 8388608  [N][64] f32
  _Float16* agg2 = (_Float16*)(p + 30553600);  // 8388608  [N][128] f16
  _Float16* agg3 = (_Float16*)(p + 38942208);  // 33554432 [N][512] f16
  _Float16* w2t  = (_Float16*)(p + 72496640);  // 32768    Bt2[128][128] f16
  _Float16* w3t  = (_Float16*)(p + 72529408);  // 524288   Bt3[512][512] f16
  // end: 73053696 B

  // 1) all weight-only prep (3x prep + 2x transpose) + cnt zeroing
  k_weights<<<NB_WEIGHTS, 256, 0, stream>>>(W1, We1, as1, ad1, ae1,
                                            W2, We2, as2, ad2, ae2,
                                            W3, We3, as3, ad3, ae3,
                                            prep1, prep2, prep3, w2t, w3t, cnt);
  // 2) bucket-CSR fill + layer-1 scores
  k_fill_s1<<<E_TOT / 256 + N_NODES / 4, 256, 0, stream>>>(ei, cnt, csr, x, prep1, ssrc, sdst);

  // 3-4) layer 1: agg then fp32 GEMM (+ layer-2 scores epilogue)
  k_attn_agg<float, 16, float><<<N_NODES / 4, 256, 0, stream>>>(x, csr, cnt, prep1, ssrc, sdst, agg1);
  k_gemm1_s2<<<dim3(1, N_NODES / 64), 128, 0, stream>>>(agg1, W1, b1, prep2, h1, ssrc, sdst);

  // 5-6) layer 2: agg then MFMA GEMM (+ layer-3 scores epilogue)
  k_attn_agg<float, 32, _Float16><<<N_NODES / 4, 256, 0, stream>>>(h1, csr, cnt, prep2, ssrc, sdst, agg2);
  k_gemm2_s3<<<dim3(1, N_NODES / 128), 256, 0, stream>>>(agg2, w2t, b2, prep3, h2, ssrc, sdst);

  // 7-8) layer 3: agg then MFMA GEMM (fp32 out, no relu)
  k_attn_agg<_Float16, 128, _Float16><<<N_NODES / 4, 256, 0, stream>>>(h2, csr, cnt, prep3, ssrc, sdst, agg3);
  k_gemm_mfma64<512, 512, false, float>
      <<<dim3(4, N_NODES / 128), 256, 0, stream>>>(agg3, w3t, b3, (float*)d_out);
}